// Round 3
// baseline (163.274 us; speedup 1.0000x reference)
//
#include <hip/hip_runtime.h>
#include <math.h>

// B=16,H=14,W=14,D=512, L=32, HID=512, A=512. fp32 throughout.
// R15: single graph-capturable kernel, block = (b, l-pair), 512 threads (8 waves).
// R14 post-mortem: 89us GPU, VALUBusy 15%, occupancy 11% -> latency-bound on
// UNCOALESCED per-lane W-row streams (64 cache lines per load instr). Fix:
// wave-per-row GEMV. A wave owns row n; lanes read W[n][lane*4] and
// W[n][256+lane*4] -> two fully-coalesced 1KB loads per row; dot against
// register-hoisted h-slices; __shfl_down butterfly reduce; lane0 writes.
// Same pattern for scores (wave per pixel row of maps). Kills ftile/red LDS
// machinery (71KB->20KB LDS, ~40 syncs->6, bank conflicts->0).
// XCD mapping: bx&7 -> b-pair per XCD; W (2MB) + maps[b] (800KB) L2-resident.

__device__ __forceinline__ float dot4(const float4 a, const float4 b) {
    return a.x*b.x + a.y*b.y + a.z*b.z + a.w*b.w;
}
__device__ __forceinline__ float rdot4(const float4 f, const float4 g, const float4 w) {
    return fmaxf(f.x+g.x, 0.f)*w.x + fmaxf(f.y+g.y, 0.f)*w.y
         + fmaxf(f.z+g.z, 0.f)*w.z + fmaxf(f.w+g.w, 0.f)*w.w;
}
__device__ __forceinline__ float wave_sum(float v) {
    v += __shfl_down(v, 32);
    v += __shfl_down(v, 16);
    v += __shfl_down(v, 8);
    v += __shfl_down(v, 4);
    v += __shfl_down(v, 2);
    v += __shfl_down(v, 1);
    return v;   // lane 0 holds the sum
}

__global__ __launch_bounds__(512) void coatt_kernel(
    const float* __restrict__ maps, const float* __restrict__ hiddens,
    const float* __restrict__ W_hidden, const float* __restrict__ b_hidden,
    const float* __restrict__ W_rect, const float* __restrict__ b_rect,
    const float* __restrict__ W_co, const float* __restrict__ b_co,
    float* __restrict__ out_co, float* __restrict__ attn_out)
{
    __shared__ __align__(16) float hidA[512], hidB[512], wv[512];
    __shared__ __align__(16) float h0[512], h1[512];       // hlin; reused as out stage
    __shared__ __align__(16) float ctx0[512], ctx1[512];
    __shared__ __align__(16) float bh[512], bc[512];
    __shared__ __align__(16) float smrow[2 * 208];

    const int tid = threadIdx.x, bx = blockIdx.x;
    const int xcd = bx & 7, idx = bx >> 3;
    const int b  = (xcd << 1) | (idx & 1);
    const int l0 = (idx >> 1) * 2;
    const int w = tid >> 6, lane = tid & 63;

    // ---- stage hiddens rows, W_rect, biases (coalesced float4) ----
    {
        const float4* HA = (const float4*)(hiddens + ((size_t)b * 32 + l0) * 512);
        const float4* HB = (const float4*)(hiddens + ((size_t)b * 32 + l0 + 1) * 512);
        const float4* WV = (const float4*)W_rect;
        const float4* BH = (const float4*)b_hidden;
        const float4* BC = (const float4*)b_co;
        if (tid < 128)      { ((float4*)hidA)[tid] = HA[tid]; ((float4*)bh)[tid] = BH[tid]; }
        else if (tid < 256) { const int t = tid - 128; ((float4*)hidB)[t] = HB[t]; ((float4*)bc)[t] = BC[t]; }
        else if (tid < 384) { const int t = tid - 256; ((float4*)wv)[t] = WV[t]; }
    }
    __syncthreads();

    const int a_lo = lane * 4, a_hi = 256 + lane * 4;

    // hoist per-lane hiddens slices (fixed for all rows)
    const float4 hA_lo = *(const float4*)&hidA[a_lo];
    const float4 hA_hi = *(const float4*)&hidA[a_hi];
    const float4 hB_lo = *(const float4*)&hidB[a_lo];
    const float4 hB_hi = *(const float4*)&hidB[a_hi];

    // ---- Phase A: hlin rows; wave w owns n = w*64 .. w*64+63 ----
    #pragma unroll 4
    for (int i = 0; i < 64; ++i) {
        const int n = (w << 6) + i;
        const float* Wr = W_hidden + (size_t)n * 512;
        const float4 wa = *(const float4*)(Wr + a_lo);
        const float4 wb = *(const float4*)(Wr + a_hi);
        float s0 = dot4(wa, hA_lo) + dot4(wb, hA_hi);
        float s1 = dot4(wa, hB_lo) + dot4(wb, hB_hi);
        s0 = wave_sum(s0);
        s1 = wave_sum(s1);
        if (lane == 0) { const float bi = bh[n]; h0[n] = s0 + bi; h1[n] = s1 + bi; }
    }
    __syncthreads();

    // hoist per-lane hlin + W_rect slices for scores
    const float4 g0_lo = *(const float4*)&h0[a_lo];
    const float4 g0_hi = *(const float4*)&h0[a_hi];
    const float4 g1_lo = *(const float4*)&h1[a_lo];
    const float4 g1_hi = *(const float4*)&h1[a_hi];
    const float4 w_lo  = *(const float4*)&wv[a_lo];
    const float4 w_hi  = *(const float4*)&wv[a_hi];
    const float br = b_rect[0];
    const float* mb = maps + (size_t)b * 196 * 512;
    __syncthreads();                 // h0/h1 hoisted everywhere; safe to reuse later

    // ---- scores: wave w owns pixel rows p = w, w+8, ... ----
    for (int p = w; p < 196; p += 8) {
        const float* fr = mb + (size_t)p * 512;
        const float4 fa = *(const float4*)(fr + a_lo);
        const float4 fb = *(const float4*)(fr + a_hi);
        float s0 = rdot4(fa, g0_lo, w_lo) + rdot4(fb, g0_hi, w_hi);
        float s1 = rdot4(fa, g1_lo, w_lo) + rdot4(fb, g1_hi, w_hi);
        s0 = wave_sum(s0);
        s1 = wave_sum(s1);
        if (lane == 0) { smrow[p] = s0 + br; smrow[208 + p] = s1 + br; }
    }
    __syncthreads();

    // ---- softmax: wave 0 -> l0, wave 1 -> l0+1 ----
    if (w < 2) {
        float v[4];
        #pragma unroll
        for (int i = 0; i < 4; ++i) {
            const int p = lane + 64 * i;
            v[i] = (p < 196) ? smrow[w * 208 + p] : -INFINITY;
        }
        float m = fmaxf(fmaxf(v[0], v[1]), fmaxf(v[2], v[3]));
        for (int off = 32; off > 0; off >>= 1) m = fmaxf(m, __shfl_down(m, off));
        m = __shfl(m, 0);
        float e[4], ssum = 0.f;
        #pragma unroll
        for (int i = 0; i < 4; ++i) {
            const int p = lane + 64 * i;
            e[i] = (p < 196) ? __expf(v[i] - m) : 0.f;
            ssum += e[i];
        }
        for (int off = 32; off > 0; off >>= 1) ssum += __shfl_down(ssum, off);
        ssum = __shfl(ssum, 0);
        const float inv = 1.f / ssum;
        float* ao = attn_out + ((size_t)b * 32 + l0 + w) * 196;
        #pragma unroll
        for (int i = 0; i < 4; ++i) {
            const int p = lane + 64 * i;
            if (p < 196) {
                const float at = e[i] * inv;
                smrow[w * 208 + p] = at;
                ao[p] = at;
            }
        }
    }
    __syncthreads();

    // ---- ctx: thread owns col d = tid; coalesced stream over maps (L2-hit) ----
    {
        float a0 = 0.f, c0 = 0.f;
        #pragma unroll 4
        for (int p = 0; p < 196; ++p) {
            const float f = mb[(size_t)p * 512 + tid];
            a0 += smrow[p] * f;
            c0 += smrow[208 + p] * f;
        }
        ctx0[tid] = a0;
        ctx1[tid] = c0;
    }
    __syncthreads();

    // hoist per-lane ctx slices
    const float4 cA_lo = *(const float4*)&ctx0[a_lo];
    const float4 cA_hi = *(const float4*)&ctx0[a_hi];
    const float4 cB_lo = *(const float4*)&ctx1[a_lo];
    const float4 cB_hi = *(const float4*)&ctx1[a_hi];

    // ---- Phase C: out rows; wave w owns n = w*64 .. w*64+63; stage into h0/h1 ----
    #pragma unroll 4
    for (int i = 0; i < 64; ++i) {
        const int n = (w << 6) + i;
        const float* Wr = W_co + (size_t)n * 512;
        const float4 wa = *(const float4*)(Wr + a_lo);
        const float4 wb = *(const float4*)(Wr + a_hi);
        float s0 = dot4(wa, cA_lo) + dot4(wb, cA_hi);
        float s1 = dot4(wa, cB_lo) + dot4(wb, cB_hi);
        s0 = wave_sum(s0);
        s1 = wave_sum(s1);
        if (lane == 0) {
            const float bco = bc[n];
            h0[n] = (s0 + bco) * hidA[n];
            h1[n] = (s1 + bco) * hidB[n];
        }
    }
    __syncthreads();

    // ---- coalesced final store ----
    {
        float* o0 = out_co + ((size_t)b * 32 + l0) * 512;
        float* o1 = o0 + 512;
        if (tid < 128)      ((float4*)o0)[tid] = ((const float4*)h0)[tid];
        else if (tid < 256) ((float4*)o1)[tid - 128] = ((const float4*)h1)[tid - 128];
    }
}

extern "C" void kernel_launch(void* const* d_in, const int* in_sizes, int n_in,
                              void* d_out, int out_size, void* d_ws, size_t ws_size,
                              hipStream_t stream)
{
    const float* maps     = (const float*)d_in[0];
    const float* hiddens  = (const float*)d_in[1];
    const float* W_hidden = (const float*)d_in[2];
    const float* b_hidden = (const float*)d_in[3];
    const float* W_rect   = (const float*)d_in[4];
    const float* b_rect   = (const float*)d_in[5];
    const float* W_co     = (const float*)d_in[6];
    const float* b_co     = (const float*)d_in[7];

    float* out_co   = (float*)d_out;                    // (512,512)
    float* out_attn = out_co + (size_t)512 * 512;       // (512,196)

    hipLaunchKernelGGL(coatt_kernel, dim3(256), dim3(512), 0, stream,
                       maps, hiddens, W_hidden, b_hidden, W_rect, b_rect,
                       W_co, b_co, out_co, out_attn);
}

// Round 4
// 148.307 us; speedup vs baseline: 1.1009x; 1.1009x over previous
//
#include <hip/hip_runtime.h>
#include <math.h>

// B=16,H=14,W=14,D=512, L=32, HID=512, A=512.
// R16: ONE regular (graph-capturable) kernel + hand-rolled grid barrier.
// R15 post-mortem: block-local fusion duplicates W 32x per XCD (64 MB L2 floor
// ~15us) and per-row shuffle-GEMV is a 12-deep dependent chain at 2 waves/SIMD
// -> 110us. Fix: restore R12's traffic-optimal tiled decomposition
//   GEMM1 (hlin, MFMA 32x32 tiles) -> mid (scores/softmax/ctx) -> GEMM2
// inside one kernel, separated by a spin grid-barrier:
//  - grid 256 x 512thr, LDS 67KB -> >=2 blocks/CU capacity -> all 256 blocks
//    co-resident regardless of placement => barrier cannot deadlock.
//  - counter is a __device__ global: zero at module load, NOT poisoned by the
//    harness (it only fills d_ws/d_out), monotone across graph replays; epoch
//    alignment holds because launches are stream-serialized (256 adds/barrier).
//  - agent-scope acq/rel atomics + __threadfence for cross-XCD visibility of
//    hlin/ctx in workspace.

typedef __attribute__((ext_vector_type(8))) short short8;
typedef __attribute__((ext_vector_type(4))) float f32x4;

__device__ unsigned g_bar = 0;   // module .bss: zeroed once at load, grows forever

__device__ __forceinline__ void grid_barrier() {
    __syncthreads();                       // all block stores done, tid0 proceeds
    if (threadIdx.x == 0) {
        __threadfence();                   // release: push ws writes (wbl2)
        unsigned old = __hip_atomic_fetch_add(&g_bar, 1u, __ATOMIC_ACQ_REL,
                                              __HIP_MEMORY_SCOPE_AGENT);
        const unsigned tgt = (old & ~255u) + 256u;
        while (__hip_atomic_load(&g_bar, __ATOMIC_ACQUIRE,
                                 __HIP_MEMORY_SCOPE_AGENT) < tgt)
            __builtin_amdgcn_s_sleep(2);
        __threadfence();                   // acquire: drop stale L2 lines
    }
    __syncthreads();                       // block waits on tid0; orders loads
}

__device__ __forceinline__ unsigned f2bf_u(float x) {
    union { float f; unsigned u; } c; c.f = x;
    return (c.u + 0x7FFFu + ((c.u >> 16) & 1u)) >> 16;   // RNE, finite inputs
}
__device__ __forceinline__ unsigned pack2(float lo, float hi) {
    return f2bf_u(lo) | (f2bf_u(hi) << 16);
}
__device__ __forceinline__ uint4 pack8(const float4 a, const float4 b) {
    uint4 r;
    r.x = pack2(a.x, a.y); r.y = pack2(a.z, a.w);
    r.z = pack2(b.x, b.y); r.w = pack2(b.z, b.w);
    return r;
}
__device__ __forceinline__ float rdot4(const float4 f, const float4 g, const float4 w) {
    return fmaxf(f.x+g.x, 0.f)*w.x + fmaxf(f.y+g.y, 0.f)*w.y
         + fmaxf(f.z+g.z, 0.f)*w.z + fmaxf(f.w+g.w, 0.f)*w.w;
}
__device__ __forceinline__ float wave_sum(float v) {
    v += __shfl_down(v, 32); v += __shfl_down(v, 16); v += __shfl_down(v, 8);
    v += __shfl_down(v, 4);  v += __shfl_down(v, 2);  v += __shfl_down(v, 1);
    return v;   // lane 0 holds the sum
}

// ---- GEMM phase: C = A(512,512)_f32 . B(512,512)_f32^T + bias[n] [* hmul] ----
// 512 threads: tile (m0,n0) 32x32; 8 waves split K (2 chunks of 32 each) + LDS reduce.
template<int HMUL>
__device__ __forceinline__ void gemm_body(char* smem,
    const float* __restrict__ Af, const float* __restrict__ Bf,
    const float* __restrict__ bias, const float* __restrict__ hmul,
    float* __restrict__ C)
{
    uint4* As = (uint4*)smem;               // 2048 slots (32KB)
    uint4* Bs = (uint4*)(smem + 32768);     // 2048 slots (32KB)
    float* red = (float*)smem;              // overlays As after sync (32KB)
    const int tid = threadIdx.x, bid = blockIdx.x;

    const int m0 = (bid >> 4) * 32, n0 = (bid & 15) * 32;
    #pragma unroll
    for (int j = 0; j < 4; ++j) {
        const int S = tid + 512 * j;
        const int i = S >> 6, ln = S & 63;
        const int t = i & 1, s = i >> 1;
        const int row  = t * 16 + (ln & 15);
        const int col8 = s * 4 + (ln >> 4);
        const float* ap = Af + (size_t)(m0 + row) * 512 + col8 * 8;
        const float* bp = Bf + (size_t)(n0 + row) * 512 + col8 * 8;
        As[S] = pack8(*(const float4*)ap, *(const float4*)(ap + 4));
        Bs[S] = pack8(*(const float4*)bp, *(const float4*)(bp + 4));
    }
    __syncthreads();

    const int w = tid >> 6, ln = tid & 63;
    f32x4 acc[4];                            // fo = tm*2+tn
    #pragma unroll
    for (int fo = 0; fo < 4; ++fo) acc[fo] = (f32x4){0.f,0.f,0.f,0.f};
    #pragma unroll
    for (int sl = 0; sl < 2; ++sl) {
        const int s = 2 * w + sl;            // k-chunk 0..15
        const short8 a0 = *(const short8*)&As[(2*s+0)*64 + ln];
        const short8 a1 = *(const short8*)&As[(2*s+1)*64 + ln];
        const short8 b0 = *(const short8*)&Bs[(2*s+0)*64 + ln];
        const short8 b1 = *(const short8*)&Bs[(2*s+1)*64 + ln];
        acc[0] = __builtin_amdgcn_mfma_f32_16x16x32_bf16(a0, b0, acc[0], 0, 0, 0);
        acc[1] = __builtin_amdgcn_mfma_f32_16x16x32_bf16(a0, b1, acc[1], 0, 0, 0);
        acc[2] = __builtin_amdgcn_mfma_f32_16x16x32_bf16(a1, b0, acc[2], 0, 0, 0);
        acc[3] = __builtin_amdgcn_mfma_f32_16x16x32_bf16(a1, b1, acc[3], 0, 0, 0);
    }
    __syncthreads();                         // done reading As/Bs
    #pragma unroll
    for (int fo = 0; fo < 4; ++fo)
        #pragma unroll
        for (int r = 0; r < 4; ++r)
            red[w*1024 + fo*256 + r*64 + ln] = acc[fo][r];
    __syncthreads();
    #pragma unroll
    for (int jj = 0; jj < 2; ++jj) {
        const int o = tid + 512 * jj;        // 0..1023 outputs
        float v = 0.f;
        #pragma unroll
        for (int ww = 0; ww < 8; ++ww) v += red[ww*1024 + o];
        const int fo = o >> 8, r = (o >> 6) & 3, l2 = o & 63;
        // C/D layout: col = lane&15, row = (lane>>4)*4 + reg [m89-verified]
        const int m = m0 + (fo >> 1) * 16 + ((l2 >> 4) << 2) + r;
        const int n = n0 + (fo & 1) * 16 + (l2 & 15);
        v += bias[n];
        if (HMUL) v *= hmul[(size_t)m * 512 + n];
        C[(size_t)m * 512 + n] = v;
    }
}

// ---- mid phase: block (XCD-affine) owns (b, l0, l0+1) ----
__device__ __forceinline__ void mid_body(float* smrow,
    const float* __restrict__ maps, const float* __restrict__ hlin,
    const float* __restrict__ W_rect, const float* __restrict__ b_rect,
    float* __restrict__ attn_out, float* __restrict__ ctx_out)
{
    const int tid = threadIdx.x, bx = blockIdx.x;
    const int xcd = bx & 7, idx = bx >> 3;
    const int b  = (xcd << 1) | (idx & 1);   // maps[b] (800KB/XCD) L2-resident
    const int l0 = (idx >> 1) * 2;
    const int w = tid >> 6, lane = tid & 63;
    const int a_lo = lane * 4, a_hi = 256 + lane * 4;

    // per-lane hlin/W_rect slices straight from ws/global (coalesced float4)
    const float* h0p = hlin + ((size_t)b * 32 + l0) * 512;
    const float* h1p = h0p + 512;
    const float4 g0_lo = *(const float4*)(h0p + a_lo);
    const float4 g0_hi = *(const float4*)(h0p + a_hi);
    const float4 g1_lo = *(const float4*)(h1p + a_lo);
    const float4 g1_hi = *(const float4*)(h1p + a_hi);
    const float4 w_lo  = *(const float4*)(W_rect + a_lo);
    const float4 w_hi  = *(const float4*)(W_rect + a_hi);
    const float br = b_rect[0];
    const float* mb = maps + (size_t)b * 196 * 512;

    // scores: wave w owns p === w (mod 8); 2 rows per iter for load ILP
    for (int p0 = w; p0 < 196; p0 += 16) {
        const int p1 = p0 + 8;
        const float* fr0 = mb + (size_t)p0 * 512;
        const float4 fa0 = *(const float4*)(fr0 + a_lo);
        const float4 fb0 = *(const float4*)(fr0 + a_hi);
        float s00 = rdot4(fa0, g0_lo, w_lo) + rdot4(fb0, g0_hi, w_hi);
        float s01 = rdot4(fa0, g1_lo, w_lo) + rdot4(fb0, g1_hi, w_hi);
        float s10 = 0.f, s11 = 0.f;
        if (p1 < 196) {
            const float* fr1 = mb + (size_t)p1 * 512;
            const float4 fa1 = *(const float4*)(fr1 + a_lo);
            const float4 fb1 = *(const float4*)(fr1 + a_hi);
            s10 = rdot4(fa1, g0_lo, w_lo) + rdot4(fb1, g0_hi, w_hi);
            s11 = rdot4(fa1, g1_lo, w_lo) + rdot4(fb1, g1_hi, w_hi);
        }
        s00 = wave_sum(s00); s01 = wave_sum(s01);
        s10 = wave_sum(s10); s11 = wave_sum(s11);
        if (lane == 0) {
            smrow[p0] = s00 + br; smrow[208 + p0] = s01 + br;
            if (p1 < 196) { smrow[p1] = s10 + br; smrow[208 + p1] = s11 + br; }
        }
    }
    __syncthreads();

    // softmax: wave 0 -> l0, wave 1 -> l0+1
    if (w < 2) {
        float v[4];
        #pragma unroll
        for (int i = 0; i < 4; ++i) {
            const int p = lane + 64 * i;
            v[i] = (p < 196) ? smrow[w * 208 + p] : -INFINITY;
        }
        float m = fmaxf(fmaxf(v[0], v[1]), fmaxf(v[2], v[3]));
        for (int off = 32; off > 0; off >>= 1) m = fmaxf(m, __shfl_down(m, off));
        m = __shfl(m, 0);
        float e[4], ssum = 0.f;
        #pragma unroll
        for (int i = 0; i < 4; ++i) {
            const int p = lane + 64 * i;
            e[i] = (p < 196) ? __expf(v[i] - m) : 0.f;
            ssum += e[i];
        }
        for (int off = 32; off > 0; off >>= 1) ssum += __shfl_down(ssum, off);
        ssum = __shfl(ssum, 0);
        const float inv = 1.f / ssum;
        float* ao = attn_out + ((size_t)b * 32 + l0 + w) * 196;
        #pragma unroll
        for (int i = 0; i < 4; ++i) {
            const int p = lane + 64 * i;
            if (p < 196) {
                const float at = e[i] * inv;
                smrow[w * 208 + p] = at;
                ao[p] = at;
            }
        }
    }
    __syncthreads();

    // ctx: thread owns col d = tid; 4 partial sums break the fp add chain
    {
        const int d = tid;
        float a0=0.f,a1=0.f,a2=0.f,a3=0.f, c0=0.f,c1=0.f,c2=0.f,c3=0.f;
        for (int p = 0; p < 196; p += 4) {
            const float f0 = mb[(size_t)(p+0)*512 + d];
            const float f1 = mb[(size_t)(p+1)*512 + d];
            const float f2 = mb[(size_t)(p+2)*512 + d];
            const float f3 = mb[(size_t)(p+3)*512 + d];
            a0 += smrow[p+0]*f0; a1 += smrow[p+1]*f1;
            a2 += smrow[p+2]*f2; a3 += smrow[p+3]*f3;
            c0 += smrow[208+p+0]*f0; c1 += smrow[208+p+1]*f1;
            c2 += smrow[208+p+2]*f2; c3 += smrow[208+p+3]*f3;
        }
        float* cx = ctx_out + ((size_t)b * 32 + l0) * 512;
        cx[d]       = (a0 + a1) + (a2 + a3);
        cx[512 + d] = (c0 + c1) + (c2 + c3);
    }
}

__global__ __launch_bounds__(512) void coatt_fused(
    const float* __restrict__ maps, const float* __restrict__ hiddens,
    const float* __restrict__ W_hidden, const float* __restrict__ b_hidden,
    const float* __restrict__ W_rect, const float* __restrict__ b_rect,
    const float* __restrict__ W_co, const float* __restrict__ b_co,
    float* __restrict__ out_co, float* __restrict__ attn_out,
    float* __restrict__ hlin_ws, float* __restrict__ ctx_ws)
{
    __shared__ __align__(16) char smem[65536];
    __shared__ __align__(16) float smrow[2 * 208];   // total LDS 67.2KB -> 2 blocks/CU cap

    // 1) hlin = hiddens @ W_hidden^T + b_hidden  (tiled MFMA, 128KB/block traffic)
    gemm_body<0>(smem, hiddens, W_hidden, b_hidden, (const float*)nullptr, hlin_ws);
    grid_barrier();
    // 2) scores -> softmax (-> attn_out) -> ctx (-> ws)
    mid_body(smrow, maps, hlin_ws, W_rect, b_rect, attn_out, ctx_ws);
    grid_barrier();
    // 3) out = (ctx @ W_co^T + b_co) * hiddens
    gemm_body<1>(smem, ctx_ws, W_co, b_co, hiddens, out_co);
}

extern "C" void kernel_launch(void* const* d_in, const int* in_sizes, int n_in,
                              void* d_out, int out_size, void* d_ws, size_t ws_size,
                              hipStream_t stream)
{
    const float* maps     = (const float*)d_in[0];
    const float* hiddens  = (const float*)d_in[1];
    const float* W_hidden = (const float*)d_in[2];
    const float* b_hidden = (const float*)d_in[3];
    const float* W_rect   = (const float*)d_in[4];
    const float* b_rect   = (const float*)d_in[5];
    const float* W_co     = (const float*)d_in[6];
    const float* b_co     = (const float*)d_in[7];

    float* out_co   = (float*)d_out;                    // (512,512)
    float* out_attn = out_co + (size_t)512 * 512;       // (512,196)
    float* hlin     = (float*)d_ws;                     // (512,512) fp32
    float* ctx      = hlin + (size_t)512 * 512;         // (512,512) fp32

    hipLaunchKernelGGL(coatt_fused, dim3(256), dim3(512), 0, stream,
                       maps, hiddens, W_hidden, b_hidden, W_rect, b_rect,
                       W_co, b_co, out_co, out_attn, hlin, ctx);
}